// Round 2
// baseline (1644.173 us; speedup 1.0000x reference)
//
#include <hip/hip_runtime.h>
#include <math.h>

#define LOG2E 1.4426950408889634f

// sizes fixed by the problem
#define BSZ 8
#define SEQ 2048
#define DM  768
#define NST 64
#define DTR 128

__device__ __forceinline__ float softplusf(float x) {
  return x > 20.0f ? x : log1pf(expf(x));
}

// ---------------------------------------------------------------------------
// Kernel 1: causal depthwise conv1d (K=4, left-pad 3) + bias + SiLU
// x (B,L,D) -> xc (B,L,D).  float4 over d.
// ---------------------------------------------------------------------------
__global__ __launch_bounds__(256) void conv_silu_kernel(
    const float* __restrict__ x, const float* __restrict__ w,
    const float* __restrict__ cb, float* __restrict__ xc)
{
  int idx = blockIdx.x * 256 + threadIdx.x;      // over B*L*(D/4)
  if (idx >= BSZ * SEQ * (DM / 4)) return;
  int d4 = idx % (DM / 4);
  int bl = idx / (DM / 4);                       // b*SEQ + l
  int l  = bl % SEQ;
  int d0 = d4 * 4;
  const float* xp = x + (size_t)bl * DM + d0;
  float4 acc = *(const float4*)(cb + d0);        // bias init
  #pragma unroll
  for (int k = 0; k < 4; ++k) {
    int lk = l + k - 3;
    if (lk >= 0) {
      float4 xv = *(const float4*)(xp + (k - 3) * DM);
      acc.x = fmaf(xv.x, w[(d0 + 0) * 4 + k], acc.x);
      acc.y = fmaf(xv.y, w[(d0 + 1) * 4 + k], acc.y);
      acc.z = fmaf(xv.z, w[(d0 + 2) * 4 + k], acc.z);
      acc.w = fmaf(xv.w, w[(d0 + 3) * 4 + k], acc.w);
    }
  }
  // SiLU: v * sigmoid(v)
  acc.x = acc.x / (1.0f + exp2f(-acc.x * LOG2E));
  acc.y = acc.y / (1.0f + exp2f(-acc.y * LOG2E));
  acc.z = acc.z / (1.0f + exp2f(-acc.z * LOG2E));
  acc.w = acc.w / (1.0f + exp2f(-acc.w * LOG2E));
  *(float4*)(xc + (size_t)bl * DM + d0) = acc;
}

// ---------------------------------------------------------------------------
// Generic fp32 tiled GEMM: C(M,N) = A(M,K) * Bw(K,N), row-major, all dims
// divisible by tile sizes here. EPI==1: C = softplus(C + bias[n]).
// BM=128 BN=64 BK=16, 256 threads, 8x4 accum per thread.
// ---------------------------------------------------------------------------
template <int EPI>
__global__ __launch_bounds__(256) void gemm_f32(
    const float* __restrict__ A, int lda,
    const float* __restrict__ Bw, int ldb,
    float* __restrict__ C, int ldc,
    int M, int N, int K, const float* __restrict__ bias)
{
  constexpr int BM = 128, BN = 64, BK = 16;
  __shared__ float As[BK][132];   // A^T tile, padded row (132*4B = 33*16B, keeps float4 align)
  __shared__ float Bs[BK][BN];

  const int tid = threadIdx.x;
  const int tn = tid & 15;        // col group (4 cols)
  const int tm = tid >> 4;        // row group (8 rows)
  const int m0 = blockIdx.x * BM;
  const int n0 = blockIdx.y * BN;

  // A tile loads: 128x16, thread -> rows (tid>>2, +64), cols (tid&3)*4
  const int ar = tid >> 2;
  const int ac = (tid & 3) << 2;
  const float* Ap = A + (size_t)(m0 + ar) * lda + ac;
  // B tile loads: 16x64, thread -> row tid>>4, col (tid&15)*4
  const int br = tid >> 4;
  const int bc = (tid & 15) << 2;
  const float* Bp = Bw + (size_t)br * ldb + n0 + bc;

  float acc[8][4] = {};
  float4 a0 = *(const float4*)Ap;
  float4 a1 = *(const float4*)(Ap + (size_t)64 * lda);
  float4 b0 = *(const float4*)Bp;

  const int nkt = K / BK;
  for (int kt = 0; kt < nkt; ++kt) {
    __syncthreads();
    As[ac + 0][ar] = a0.x; As[ac + 1][ar] = a0.y;
    As[ac + 2][ar] = a0.z; As[ac + 3][ar] = a0.w;
    As[ac + 0][ar + 64] = a1.x; As[ac + 1][ar + 64] = a1.y;
    As[ac + 2][ar + 64] = a1.z; As[ac + 3][ar + 64] = a1.w;
    *(float4*)&Bs[br][bc] = b0;
    __syncthreads();
    if (kt + 1 < nkt) {
      Ap += BK;
      Bp += (size_t)BK * ldb;
      a0 = *(const float4*)Ap;
      a1 = *(const float4*)(Ap + (size_t)64 * lda);
      b0 = *(const float4*)Bp;
    }
    #pragma unroll
    for (int k = 0; k < BK; ++k) {
      float4 t0 = *(const float4*)&As[k][tm * 8];
      float4 t1 = *(const float4*)&As[k][tm * 8 + 4];
      float4 tb = *(const float4*)&Bs[k][tn * 4];
      float av[8] = {t0.x, t0.y, t0.z, t0.w, t1.x, t1.y, t1.z, t1.w};
      float bv[4] = {tb.x, tb.y, tb.z, tb.w};
      #pragma unroll
      for (int i = 0; i < 8; ++i)
        #pragma unroll
        for (int j = 0; j < 4; ++j)
          acc[i][j] = fmaf(av[i], bv[j], acc[i][j]);
    }
  }

  #pragma unroll
  for (int i = 0; i < 8; ++i) {
    int row = m0 + tm * 8 + i;
    float* cp = C + (size_t)row * ldc + n0 + tn * 4;
    float4 o;
    if (EPI == 1) {
      o.x = softplusf(acc[i][0] + bias[n0 + tn * 4 + 0]);
      o.y = softplusf(acc[i][1] + bias[n0 + tn * 4 + 1]);
      o.z = softplusf(acc[i][2] + bias[n0 + tn * 4 + 2]);
      o.w = softplusf(acc[i][3] + bias[n0 + tn * 4 + 3]);
    } else {
      o.x = acc[i][0]; o.y = acc[i][1]; o.z = acc[i][2]; o.w = acc[i][3];
    }
    *(float4*)cp = o;
  }
}

// ---------------------------------------------------------------------------
// Kernel 4: selective scan.
// Wave layout: 16 lane-groups x 4 n-slots; lane = (d_sub<<4) | n_grp.
// Each wave owns 4 d-channels, full N=64 state in regs (4 per lane).
// Per t: dA = exp2(dt * (-exp(A_log))*log2e), state = dA*state + (dt*u)*B,
//        y = sum_n state*C  (16-lane xor-shuffle tree, batched x4 for ILP).
// u is read from xc and y written in-place over it (same (b,t,d) slot).
// Loads software-pipelined 8 timesteps ahead (2 batches of 4).
// ---------------------------------------------------------------------------
__global__ __launch_bounds__(256) void scan_kernel(
    const float* __restrict__ xdbl, const float* __restrict__ dt,
    float* __restrict__ u_y, const float* __restrict__ A_log)
{
  const int L = SEQ;
  const int lane = threadIdx.x & 63;
  const int wv = threadIdx.x >> 6;
  const int b = blockIdx.y;
  const int d = blockIdx.x * 16 + wv * 4 + (lane >> 4);
  const int nb = (lane & 15) << 2;

  float aj[4];
  #pragma unroll
  for (int j = 0; j < 4; ++j)
    aj[j] = -expf(A_log[d * NST + nb + j]) * LOG2E;

  float s0 = 0.f, s1 = 0.f, s2 = 0.f, s3 = 0.f;
  const float* Bp  = xdbl + (size_t)b * L * 256 + DTR + nb;   // B cols 128..191
  const float* Cp  = Bp + NST;                                // C cols 192..255
  const float* dtp = dt + (size_t)b * L * DM + d;
  float* up        = u_y + (size_t)b * L * DM + d;

  float4 Ba[4], Ca[4], Bb[4], Cb[4];
  float dta[4], ua[4], dtb[4], ub[4];

#define LOADB(Bv, Cv, dtv, uv, T) do {                        \
    _Pragma("unroll")                                         \
    for (int q = 0; q < 4; ++q) {                             \
      size_t r = (size_t)((T) + q);                           \
      Bv[q]  = *(const float4*)(Bp + r * 256);                \
      Cv[q]  = *(const float4*)(Cp + r * 256);                \
      dtv[q] = dtp[r * DM];                                   \
      uv[q]  = up[r * DM];                                    \
    } } while (0)

#define COMPUTE(Bv, Cv, dtv, uv, T) do {                      \
    float p[4];                                               \
    _Pragma("unroll")                                         \
    for (int q = 0; q < 4; ++q) {                             \
      float dtq = dtv[q];                                     \
      float dtu = dtq * uv[q];                                \
      float e0 = exp2f(dtq * aj[0]);                          \
      float e1 = exp2f(dtq * aj[1]);                          \
      float e2 = exp2f(dtq * aj[2]);                          \
      float e3 = exp2f(dtq * aj[3]);                          \
      s0 = fmaf(e0, s0, dtu * Bv[q].x);                       \
      s1 = fmaf(e1, s1, dtu * Bv[q].y);                       \
      s2 = fmaf(e2, s2, dtu * Bv[q].z);                       \
      s3 = fmaf(e3, s3, dtu * Bv[q].w);                       \
      p[q] = (s0 * Cv[q].x + s1 * Cv[q].y)                    \
           + (s2 * Cv[q].z + s3 * Cv[q].w);                   \
    }                                                         \
    _Pragma("unroll")                                         \
    for (int m = 1; m < 16; m <<= 1) {                        \
      p[0] += __shfl_xor(p[0], m);                            \
      p[1] += __shfl_xor(p[1], m);                            \
      p[2] += __shfl_xor(p[2], m);                            \
      p[3] += __shfl_xor(p[3], m);                            \
    }                                                         \
    if ((lane & 15) == 0) {                                   \
      up[(size_t)((T) + 0) * DM] = p[0];                      \
      up[(size_t)((T) + 1) * DM] = p[1];                      \
      up[(size_t)((T) + 2) * DM] = p[2];                      \
      up[(size_t)((T) + 3) * DM] = p[3];                      \
    } } while (0)

  LOADB(Ba, Ca, dta, ua, 0);
  LOADB(Bb, Cb, dtb, ub, 4);
  for (int tb = 0; tb < L; tb += 8) {
    int tA = (tb + 8  < L) ? tb + 8  : 0;  // wrap-safe dummy prefetch at tail
    int tB = (tb + 12 < L) ? tb + 12 : 0;
    COMPUTE(Ba, Ca, dta, ua, tb);
    LOADB(Ba, Ca, dta, ua, tA);
    COMPUTE(Bb, Cb, dtb, ub, tb + 4);
    LOADB(Bb, Cb, dtb, ub, tB);
  }
#undef LOADB
#undef COMPUTE
}

// ---------------------------------------------------------------------------
extern "C" void kernel_launch(void* const* d_in, const int* in_sizes, int n_in,
                              void* d_out, int out_size, void* d_ws, size_t ws_size,
                              hipStream_t stream) {
  const float* x         = (const float*)d_in[0];
  const float* A_log     = (const float*)d_in[1];
  const float* x_proj_w  = (const float*)d_in[2];   // (768, 256)
  const float* dt_proj_w = (const float*)d_in[3];   // (128, 768)
  const float* dt_proj_b = (const float*)d_in[4];   // (768)
  const float* conv_w    = (const float*)d_in[5];   // (768,1,4)
  const float* conv_b    = (const float*)d_in[6];   // (768)
  const float* out_w     = (const float*)d_in[7];   // (768, 768)
  float* out = (float*)d_out;
  float* ws  = (float*)d_ws;

  const int M = BSZ * SEQ;                 // 16384 rows
  float* xc   = ws;                        // (B,L,D)  = 12582912 f
  float* xdbl = xc + (size_t)M * DM;       // (B,L,256)=  4194304 f
  float* dtb  = out;                       // dt lives in d_out (dead before final GEMM)

  // 1) conv + silu
  {
    int total = BSZ * SEQ * (DM / 4);
    conv_silu_kernel<<<(total + 255) / 256, 256, 0, stream>>>(x, conv_w, conv_b, xc);
  }
  // 2) x_dbl = xc @ x_proj_w   (16384x768 @ 768x256)
  {
    dim3 g(M / 128, 256 / 64);
    gemm_f32<0><<<g, 256, 0, stream>>>(xc, DM, x_proj_w, 256, xdbl, 256,
                                       M, 256, DM, nullptr);
  }
  // 3) dt = softplus(x_dbl[:, :128] @ dt_proj_w + b)   (16384x128 @ 128x768)
  {
    dim3 g(M / 128, DM / 64);
    gemm_f32<1><<<g, 256, 0, stream>>>(xdbl, 256, dt_proj_w, DM, dtb, DM,
                                       M, DM, DTR, dt_proj_b);
  }
  // 4) selective scan: y written in-place over xc
  {
    dim3 g(DM / 16, BSZ);
    scan_kernel<<<g, 256, 0, stream>>>(xdbl, dtb, xc, A_log);
  }
  // 5) out = y @ out_w   (16384x768 @ 768x768)
  {
    dim3 g(M / 128, DM / 64);
    gemm_f32<0><<<g, 256, 0, stream>>>(xc, DM, out_w, DM, out, DM,
                                       M, DM, DM, nullptr);
  }
}

// Round 7
// 754.009 us; speedup vs baseline: 2.1806x; 2.1806x over previous
//
#include <hip/hip_runtime.h>
#include <math.h>

#define LOG2E 1.4426950408889634f

// sizes fixed by the problem
#define BSZ 8
#define SEQ 2048
#define DM  768
#define NST 64
#define DTR 128
// chunked-scan params
#define NC  8
#define CL  (SEQ / NC)            // 256
#define BDN (BSZ * DM * NST)      // 393216

typedef __bf16 bf16x8 __attribute__((ext_vector_type(8)));
typedef float  f32x4  __attribute__((ext_vector_type(4)));

__device__ __forceinline__ float softplusf(float x) {
  return x > 20.0f ? x : log1pf(expf(x));
}
__device__ __forceinline__ float fexp2(float x) {
  return __builtin_amdgcn_exp2f(x);
}
__device__ __forceinline__ unsigned short f2bf(float f) {
  unsigned u = __float_as_uint(f);
  return (unsigned short)((u + 0x7FFFu + ((u >> 16) & 1u)) >> 16);
}
__device__ __forceinline__ float bf2f(unsigned short h) {
  return __uint_as_float(((unsigned)h) << 16);
}

// ---------------------------------------------------------------------------
// Kernel 1: causal depthwise conv1d (K=4, left-pad 3) + bias + SiLU.
// Optionally also emits bf16 hi/lo split of the output (for MFMA GEMM A).
// ---------------------------------------------------------------------------
__global__ __launch_bounds__(256) void conv_silu_kernel(
    const float* __restrict__ x, const float* __restrict__ w,
    const float* __restrict__ cb, float* __restrict__ xc,
    unsigned short* __restrict__ xh, unsigned short* __restrict__ xl)
{
  int idx = blockIdx.x * 256 + threadIdx.x;      // over B*L*(D/4)
  if (idx >= BSZ * SEQ * (DM / 4)) return;
  int d4 = idx % (DM / 4);
  int bl = idx / (DM / 4);                       // b*SEQ + l
  int l  = bl % SEQ;
  int d0 = d4 * 4;
  const float* xp = x + (size_t)bl * DM + d0;
  float4 acc = *(const float4*)(cb + d0);        // bias init
  #pragma unroll
  for (int k = 0; k < 4; ++k) {
    int lk = l + k - 3;
    if (lk >= 0) {
      float4 xv = *(const float4*)(xp + (k - 3) * DM);
      acc.x = fmaf(xv.x, w[(d0 + 0) * 4 + k], acc.x);
      acc.y = fmaf(xv.y, w[(d0 + 1) * 4 + k], acc.y);
      acc.z = fmaf(xv.z, w[(d0 + 2) * 4 + k], acc.z);
      acc.w = fmaf(xv.w, w[(d0 + 3) * 4 + k], acc.w);
    }
  }
  acc.x = acc.x / (1.0f + fexp2(-acc.x * LOG2E));
  acc.y = acc.y / (1.0f + fexp2(-acc.y * LOG2E));
  acc.z = acc.z / (1.0f + fexp2(-acc.z * LOG2E));
  acc.w = acc.w / (1.0f + fexp2(-acc.w * LOG2E));
  *(float4*)(xc + (size_t)bl * DM + d0) = acc;
  if (xh) {
    ushort4 h4, l4;
    h4.x = f2bf(acc.x); l4.x = f2bf(acc.x - bf2f(h4.x));
    h4.y = f2bf(acc.y); l4.y = f2bf(acc.y - bf2f(h4.y));
    h4.z = f2bf(acc.z); l4.z = f2bf(acc.z - bf2f(h4.z));
    h4.w = f2bf(acc.w); l4.w = f2bf(acc.w - bf2f(h4.w));
    *(ushort4*)(xh + (size_t)bl * DM + d0) = h4;
    *(ushort4*)(xl + (size_t)bl * DM + d0) = l4;
  }
}

// ---------------------------------------------------------------------------
// Weight convert: W[K][N] fp32 -> transposed bf16 hi/lo [N][K]
// ---------------------------------------------------------------------------
__global__ __launch_bounds__(256) void cvt_wT(
    const float* __restrict__ W, unsigned short* __restrict__ Th,
    unsigned short* __restrict__ Tl, int K, int N)
{
  int idx = blockIdx.x * 256 + threadIdx.x;
  if (idx >= K * N) return;
  int n = idx / K, k = idx % K;
  float v = W[(size_t)k * N + n];
  unsigned short h = f2bf(v);
  Th[idx] = h;
  Tl[idx] = f2bf(v - bf2f(h));
}

// dt_raw = x_dbl[:, 0:128] fp32 -> bf16 hi/lo [16384][128]
__global__ __launch_bounds__(256) void cvt_dtraw(
    const float* __restrict__ xdbl, unsigned short* __restrict__ dth,
    unsigned short* __restrict__ dtl)
{
  int idx = blockIdx.x * 256 + threadIdx.x;      // over 16384*32
  if (idx >= BSZ * SEQ * 32) return;
  int row = idx >> 5, c4 = (idx & 31) << 2;
  float4 v = *(const float4*)(xdbl + (size_t)row * 256 + c4);
  ushort4 h4, l4;
  h4.x = f2bf(v.x); l4.x = f2bf(v.x - bf2f(h4.x));
  h4.y = f2bf(v.y); l4.y = f2bf(v.y - bf2f(h4.y));
  h4.z = f2bf(v.z); l4.z = f2bf(v.z - bf2f(h4.z));
  h4.w = f2bf(v.w); l4.w = f2bf(v.w - bf2f(h4.w));
  *(ushort4*)(dth + (size_t)row * DTR + c4) = h4;
  *(ushort4*)(dtl + (size_t)row * DTR + c4) = l4;
}

// ---------------------------------------------------------------------------
// Split-bf16 MFMA GEMM: C(M,N) = A(M,K) * B(K,N) in ~fp32 accuracy.
// A given as bf16 hi/lo [M][K]; B given TRANSPOSED as bf16 hi/lo [N][K].
// 3-product split: ah*bh + ah*bl + al*bh (al*bl ~2^-16 rel, dropped).
// Tile 128x128, BK=32, 4 waves of 64x64, v_mfma_f32_16x16x32_bf16.
// NOTE: A/B fragment k-ordering only needs consistency (k-permutation
// cancels in the dot product); C/D layout col=lane&15,row=(lane>>4)*4+reg
// is the HW-verified mapping.
// LDS XOR block swizzle p = g ^ ((r + (r>>2)) & 3) -> 2-way max on reads.
// EPI==1: C = softplus(C + bias[n]).
// ---------------------------------------------------------------------------
template <int EPI>
__global__ __launch_bounds__(256) void gemm_bfs(
    const unsigned short* __restrict__ Ah, const unsigned short* __restrict__ Al,
    const unsigned short* __restrict__ BhT, const unsigned short* __restrict__ BlT,
    float* __restrict__ C, int K, int ldc, const float* __restrict__ bias)
{
  __shared__ unsigned short Ahs[128 * 32], Als[128 * 32];
  __shared__ unsigned short Bhs[128 * 32], Bls[128 * 32];

  const int tid  = threadIdx.x;
  const int lane = tid & 63;
  const int wv   = tid >> 6;
  const int wm   = wv >> 1, wn = wv & 1;
  const int m0   = blockIdx.x * 128, n0 = blockIdx.y * 128;

  // staging: thread covers row sr, 2x16B blocks {sg, sg+1}
  const int sr  = tid >> 1;
  const int sg  = (tid & 1) * 2;
  const int ssw = (sr + (sr >> 2)) & 3;
  const int lo0 = sr * 64 + ((sg    ) ^ ssw) * 16;   // LDS byte offsets
  const int lo1 = sr * 64 + ((sg + 1) ^ ssw) * 16;

  const unsigned short* gAh = Ah  + (size_t)(m0 + sr) * K + sg * 8;
  const unsigned short* gAl = Al  + (size_t)(m0 + sr) * K + sg * 8;
  const unsigned short* gBh = BhT + (size_t)(n0 + sr) * K + sg * 8;
  const unsigned short* gBl = BlT + (size_t)(n0 + sr) * K + sg * 8;

  // fragment-read lane constants: row r = base16 + rl, block g = lane>>4
  const int rl  = lane & 15;
  const int fsw = (((lane >> 4) ^ ((rl + (rl >> 2)) & 3)) * 16);  // byte

  f32x4 acc[4][4];
  #pragma unroll
  for (int i = 0; i < 4; ++i)
    #pragma unroll
    for (int j = 0; j < 4; ++j)
      acc[i][j] = (f32x4){0.f, 0.f, 0.f, 0.f};

  uint4 pah0 = *(const uint4*)gAh, pah1 = *(const uint4*)(gAh + 8);
  uint4 pal0 = *(const uint4*)gAl, pal1 = *(const uint4*)(gAl + 8);
  uint4 pbh0 = *(const uint4*)gBh, pbh1 = *(const uint4*)(gBh + 8);
  uint4 pbl0 = *(const uint4*)gBl, pbl1 = *(const uint4*)(gBl + 8);

  const int nk = K >> 5;
  for (int kt = 0; kt < nk; ++kt) {
    __syncthreads();
    *(uint4*)((char*)Ahs + lo0) = pah0; *(uint4*)((char*)Ahs + lo1) = pah1;
    *(uint4*)((char*)Als + lo0) = pal0; *(uint4*)((char*)Als + lo1) = pal1;
    *(uint4*)((char*)Bhs + lo0) = pbh0; *(uint4*)((char*)Bhs + lo1) = pbh1;
    *(uint4*)((char*)Bls + lo0) = pbl0; *(uint4*)((char*)Bls + lo1) = pbl1;
    __syncthreads();
    if (kt + 1 < nk) {
      gAh += 32; gAl += 32; gBh += 32; gBl += 32;
      pah0 = *(const uint4*)gAh; pah1 = *(const uint4*)(gAh + 8);
      pal0 = *(const uint4*)gAl; pal1 = *(const uint4*)(gAl + 8);
      pbh0 = *(const uint4*)gBh; pbh1 = *(const uint4*)(gBh + 8);
      pbl0 = *(const uint4*)gBl; pbl1 = *(const uint4*)(gBl + 8);
    }
    bf16x8 fah[4], fal[4], fbh[4], fbl[4];
    #pragma unroll
    for (int mt = 0; mt < 4; ++mt) {
      int ro = (wm * 64 + mt * 16 + rl) * 64 + fsw;
      fah[mt] = __builtin_bit_cast(bf16x8, *(const uint4*)((char*)Ahs + ro));
      fal[mt] = __builtin_bit_cast(bf16x8, *(const uint4*)((char*)Als + ro));
    }
    #pragma unroll
    for (int nt = 0; nt < 4; ++nt) {
      int ro = (wn * 64 + nt * 16 + rl) * 64 + fsw;
      fbh[nt] = __builtin_bit_cast(bf16x8, *(const uint4*)((char*)Bhs + ro));
      fbl[nt] = __builtin_bit_cast(bf16x8, *(const uint4*)((char*)Bls + ro));
    }
    #pragma unroll
    for (int mt = 0; mt < 4; ++mt)
      #pragma unroll
      for (int nt = 0; nt < 4; ++nt) {
        acc[mt][nt] = __builtin_amdgcn_mfma_f32_16x16x32_bf16(fah[mt], fbh[nt], acc[mt][nt], 0, 0, 0);
        acc[mt][nt] = __builtin_amdgcn_mfma_f32_16x16x32_bf16(fah[mt], fbl[nt], acc[mt][nt], 0, 0, 0);
        acc[mt][nt] = __builtin_amdgcn_mfma_f32_16x16x32_bf16(fal[mt], fbh[nt], acc[mt][nt], 0, 0, 0);
      }
  }

  const int orow = (lane >> 4) * 4;
  #pragma unroll
  for (int mt = 0; mt < 4; ++mt)
    #pragma unroll
    for (int nt = 0; nt < 4; ++nt) {
      int col = n0 + wn * 64 + nt * 16 + rl;
      float bb = (EPI == 1) ? bias[col] : 0.f;
      #pragma unroll
      for (int r = 0; r < 4; ++r) {
        int row = m0 + wm * 64 + mt * 16 + orow + r;
        float v = acc[mt][nt][r];
        if (EPI == 1) v = softplusf(v + bb);
        C[(size_t)row * ldc + col] = v;
      }
    }
}

// ---------------------------------------------------------------------------
// fp32 tiled GEMM (fallback tiers)
// ---------------------------------------------------------------------------
template <int EPI>
__global__ __launch_bounds__(256) void gemm_f32(
    const float* __restrict__ A, int lda,
    const float* __restrict__ Bw, int ldb,
    float* __restrict__ C, int ldc,
    int M, int N, int K, const float* __restrict__ bias)
{
  constexpr int BM = 128, BN = 64, BK = 16;
  __shared__ float As[BK][132];
  __shared__ float Bs[BK][BN];

  const int tid = threadIdx.x;
  const int tn = tid & 15;
  const int tm = tid >> 4;
  const int m0 = blockIdx.x * BM;
  const int n0 = blockIdx.y * BN;

  const int ar = tid >> 2;
  const int ac = (tid & 3) << 2;
  const float* Ap = A + (size_t)(m0 + ar) * lda + ac;
  const int br = tid >> 4;
  const int bc = (tid & 15) << 2;
  const float* Bp = Bw + (size_t)br * ldb + n0 + bc;

  float acc[8][4] = {};
  float4 a0 = *(const float4*)Ap;
  float4 a1 = *(const float4*)(Ap + (size_t)64 * lda);
  float4 b0 = *(const float4*)Bp;

  const int nkt = K / BK;
  for (int kt = 0; kt < nkt; ++kt) {
    __syncthreads();
    As[ac + 0][ar] = a0.x; As[ac + 1][ar] = a0.y;
    As[ac + 2][ar] = a0.z; As[ac + 3][ar] = a0.w;
    As[ac + 0][ar + 64] = a1.x; As[ac + 1][ar + 64] = a1.y;
    As[ac + 2][ar + 64] = a1.z; As[ac + 3][ar + 64] = a1.w;
    *(float4*)&Bs[br][bc] = b0;
    __syncthreads();
    if (kt + 1 < nkt) {
      Ap += BK;
      Bp += (size_t)BK * ldb;
      a0 = *(const float4*)Ap;
      a1 = *(const float4*)(Ap + (size_t)64 * lda);
      b0 = *(const float4*)Bp;
    }
    #pragma unroll
    for (int k = 0; k < BK; ++k) {
      float4 t0 = *(const float4*)&As[k][tm * 8];
      float4 t1 = *(const float4*)&As[k][tm * 8 + 4];
      float4 tb = *(const float4*)&Bs[k][tn * 4];
      float av[8] = {t0.x, t0.y, t0.z, t0.w, t1.x, t1.y, t1.z, t1.w};
      float bv[4] = {tb.x, tb.y, tb.z, tb.w};
      #pragma unroll
      for (int i = 0; i < 8; ++i)
        #pragma unroll
        for (int j = 0; j < 4; ++j)
          acc[i][j] = fmaf(av[i], bv[j], acc[i][j]);
    }
  }

  #pragma unroll
  for (int i = 0; i < 8; ++i) {
    int row = m0 + tm * 8 + i;
    float* cp = C + (size_t)row * ldc + n0 + tn * 4;
    float4 o;
    if (EPI == 1) {
      o.x = softplusf(acc[i][0] + bias[n0 + tn * 4 + 0]);
      o.y = softplusf(acc[i][1] + bias[n0 + tn * 4 + 1]);
      o.z = softplusf(acc[i][2] + bias[n0 + tn * 4 + 2]);
      o.w = softplusf(acc[i][3] + bias[n0 + tn * 4 + 3]);
    } else {
      o.x = acc[i][0]; o.y = acc[i][1]; o.z = acc[i][2]; o.w = acc[i][3];
    }
    *(float4*)cp = o;
  }
}

// ---------------------------------------------------------------------------
// Chunked selective scan (passA / combine / passC).  Lane owns 1 d x 8 n.
// ---------------------------------------------------------------------------
__global__ __launch_bounds__(256) void scan_passA(
    const float* __restrict__ xdbl, const float* __restrict__ dt,
    const float* __restrict__ u, const float* __restrict__ A_log,
    float* __restrict__ SL, float* __restrict__ Pd)
{
  const int lane = threadIdx.x & 63;
  const int wv   = threadIdx.x >> 6;
  const int b    = blockIdx.y;
  const int c    = blockIdx.z;
  const int d    = blockIdx.x * 32 + wv * 8 + (lane & 7);
  const int n0   = (lane >> 3) * 8;
  const int t0   = c * CL;

  float a[8];
  #pragma unroll
  for (int j = 0; j < 8; ++j)
    a[j] = -expf(A_log[d * NST + n0 + j]) * LOG2E;

  const float* Bp  = xdbl + (size_t)(b * SEQ + t0) * 256 + DTR + n0;
  const float* dtp = dt + (size_t)(b * SEQ + t0) * DM + d;
  const float* up  = u  + (size_t)(b * SEQ + t0) * DM + d;

  float s[8];
  #pragma unroll
  for (int j = 0; j < 8; ++j) s[j] = 0.f;
  float dtsum = 0.f;

  float4 B0 = *(const float4*)Bp;
  float4 B1 = *(const float4*)(Bp + 4);
  float dtc = *dtp, uc = *up;

#define PA_BODY() do {                                        \
    float dtu = dtc * uc;                                     \
    dtsum += dtc;                                             \
    float Bv[8] = {B0.x,B0.y,B0.z,B0.w,B1.x,B1.y,B1.z,B1.w};  \
    _Pragma("unroll")                                         \
    for (int j = 0; j < 8; ++j) {                             \
      float e = fexp2(dtc * a[j]);                            \
      s[j] = fmaf(e, s[j], dtu * Bv[j]);                      \
    } } while (0)

  for (int t = 0; t < CL - 1; ++t) {
    float4 Bn0 = *(const float4*)(Bp + 256);
    float4 Bn1 = *(const float4*)(Bp + 260);
    float dtn = dtp[DM], un = up[DM];
    PA_BODY();
    Bp += 256; dtp += DM; up += DM;
    B0 = Bn0; B1 = Bn1; dtc = dtn; uc = un;
  }
  PA_BODY();
#undef PA_BODY

  size_t o = (((size_t)c * BSZ + b) * DM + d) * NST + n0;
  #pragma unroll
  for (int j = 0; j < 8; ++j) SL[o + j] = s[j];
  #pragma unroll
  for (int j = 0; j < 8; ++j) Pd[o + j] = fexp2(a[j] * dtsum);
}

__global__ __launch_bounds__(256) void scan_combine(
    float* __restrict__ SL, const float* __restrict__ Pd)
{
  int idx = blockIdx.x * 256 + threadIdx.x;   // over B*D*N
  float s = 0.f;
  #pragma unroll
  for (int c = 0; c < NC; ++c) {
    size_t o = (size_t)c * BDN + idx;
    float sl = SL[o];
    float p  = Pd[o];
    SL[o] = s;                 // S_in[c]
    s = fmaf(p, s, sl);        // S_in[c+1]
  }
}

__global__ __launch_bounds__(256) void scan_passC(
    const float* __restrict__ xdbl, const float* __restrict__ dt,
    float* __restrict__ u_y, const float* __restrict__ A_log,
    const float* __restrict__ SL,
    unsigned short* __restrict__ yh, unsigned short* __restrict__ yl)
{
  const int lane = threadIdx.x & 63;
  const int wv   = threadIdx.x >> 6;
  const int b    = blockIdx.y;
  const int c    = blockIdx.z;
  const int d    = blockIdx.x * 32 + wv * 8 + (lane & 7);
  const int n0   = (lane >> 3) * 8;
  const int t0   = c * CL;

  float a[8];
  #pragma unroll
  for (int j = 0; j < 8; ++j)
    a[j] = -expf(A_log[d * NST + n0 + j]) * LOG2E;

  const float* Bp  = xdbl + (size_t)(b * SEQ + t0) * 256 + DTR + n0;
  const float* dtp = dt + (size_t)(b * SEQ + t0) * DM + d;
  float* up        = u_y + (size_t)(b * SEQ + t0) * DM + d;
  size_t yoff      = (size_t)(b * SEQ + t0) * DM + d;

  float s[8];
  {
    size_t o = (((size_t)c * BSZ + b) * DM + d) * NST + n0;
    #pragma unroll
    for (int j = 0; j < 8; ++j) s[j] = SL[o + j];
  }

  float4 B0 = *(const float4*)Bp;
  float4 B1 = *(const float4*)(Bp + 4);
  float4 C0 = *(const float4*)(Bp + NST);
  float4 C1 = *(const float4*)(Bp + NST + 4);
  float dtc = *dtp, uc = *up;

#define PC_BODY() do {                                        \
    float dtu = dtc * uc;                                     \
    float Bv[8] = {B0.x,B0.y,B0.z,B0.w,B1.x,B1.y,B1.z,B1.w};  \
    float Cv[8] = {C0.x,C0.y,C0.z,C0.w,C1.x,C1.y,C1.z,C1.w};  \
    float y0 = 0.f, y1 = 0.f;                                 \
    _Pragma("unroll")                                         \
    for (int j = 0; j < 8; ++j) {                             \
      float e = fexp2(dtc * a[j]);                            \
      s[j] = fmaf(e, s[j], dtu * Bv[j]);                      \
      if (j & 1) y1 = fmaf(s[j], Cv[j], y1);                  \
      else       y0 = fmaf(s[j], Cv[j], y0);                  \
    }                                                         \
    float y = y0 + y1;                                        \
    y += __shfl_xor(y, 8);                                    \
    y += __shfl_xor(y, 16);                                   \
    y += __shfl_xor(y, 32);                                   \
    if (lane < 8) {                                           \
      *up = y;                                                \
      if (yh) {                                               \
        unsigned short h = f2bf(y);                           \
        yh[yoff] = h;                                         \
        yl[yoff] = f2bf(y - bf2f(h));                         \
      }                                                       \
    } } while (0)

  for (int t = 0; t < CL - 1; ++t) {
    float4 Bn0 = *(const float4*)(Bp + 256);
    float4 Bn1 = *(const float4*)(Bp + 260);
    float4 Cn0 = *(const float4*)(Bp + 256 + NST);
    float4 Cn1 = *(const float4*)(Bp + 260 + NST);
    float dtn = dtp[DM], un = up[DM];
    PC_BODY();
    Bp += 256; dtp += DM; up += DM; yoff += DM;
    B0 = Bn0; B1 = Bn1; C0 = Cn0; C1 = Cn1; dtc = dtn; uc = un;
  }
  PC_BODY();
#undef PC_BODY
}

// ---------------------------------------------------------------------------
// Fallback monolithic scan (tier 3)
// ---------------------------------------------------------------------------
__global__ __launch_bounds__(256) void scan_kernel(
    const float* __restrict__ xdbl, const float* __restrict__ dt,
    float* __restrict__ u_y, const float* __restrict__ A_log)
{
  const int L = SEQ;
  const int lane = threadIdx.x & 63;
  const int wv = threadIdx.x >> 6;
  const int b = blockIdx.y;
  const int d = blockIdx.x * 16 + wv * 4 + (lane >> 4);
  const int nb = (lane & 15) << 2;

  float aj[4];
  #pragma unroll
  for (int j = 0; j < 4; ++j)
    aj[j] = -expf(A_log[d * NST + nb + j]) * LOG2E;

  float s0 = 0.f, s1 = 0.f, s2 = 0.f, s3 = 0.f;
  const float* Bp  = xdbl + (size_t)b * L * 256 + DTR + nb;
  const float* Cp  = Bp + NST;
  const float* dtp = dt + (size_t)b * L * DM + d;
  float* up        = u_y + (size_t)b * L * DM + d;

  float4 Ba[4], Ca[4], Bb[4], Cb[4];
  float dta[4], ua[4], dtb[4], ub[4];

#define LOADB(Bv, Cv, dtv, uv, T) do {                        \
    _Pragma("unroll")                                         \
    for (int q = 0; q < 4; ++q) {                             \
      size_t r = (size_t)((T) + q);                           \
      Bv[q]  = *(const float4*)(Bp + r * 256);                \
      Cv[q]  = *(const float4*)(Cp + r * 256);                \
      dtv[q] = dtp[r * DM];                                   \
      uv[q]  = up[r * DM];                                    \
    } } while (0)

#define COMPUTE(Bv, Cv, dtv, uv, T) do {                      \
    float p[4];                                               \
    _Pragma("unroll")                                         \
    for (int q = 0; q < 4; ++q) {                             \
      float dtq = dtv[q];                                     \
      float dtu = dtq * uv[q];                                \
      float e0 = fexp2(dtq * aj[0]);                          \
      float e1 = fexp2(dtq * aj[1]);                          \
      float e2 = fexp2(dtq * aj[2]);                          \
      float e3 = fexp2(dtq * aj[3]);                          \
      s0 = fmaf(e0, s0, dtu * Bv[q].x);                       \
      s1 = fmaf(e1, s1, dtu * Bv[q].y);                       \
      s2 = fmaf(e2, s2, dtu * Bv[q].z);                       \
      s3 = fmaf(e3, s3, dtu * Bv[q].w);                       \
      p[q] = (s0 * Cv[q].x + s1 * Cv[q].y)                    \
           + (s2 * Cv[q].z + s3 * Cv[q].w);                   \
    }                                                         \
    _Pragma("unroll")                                         \
    for (int m = 1; m < 16; m <<= 1) {                        \
      p[0] += __shfl_xor(p[0], m);                            \
      p[1] += __shfl_xor(p[1], m);                            \
      p[2] += __shfl_xor(p[2], m);                            \
      p[3] += __shfl_xor(p[3], m);                            \
    }                                                         \
    if ((lane & 15) == 0) {                                   \
      up[(size_t)((T) + 0) * DM] = p[0];                      \
      up[(size_t)((T) + 1) * DM] = p[1];                      \
      up[(size_t)((T) + 2) * DM] = p[2];                      \
      up[(size_t)((T) + 3) * DM] = p[3];                      \
    } } while (0)

  LOADB(Ba, Ca, dta, ua, 0);
  LOADB(Bb, Cb, dtb, ub, 4);
  for (int tb = 0; tb < L; tb += 8) {
    int tA = (tb + 8  < L) ? tb + 8  : 0;
    int tB = (tb + 12 < L) ? tb + 12 : 0;
    COMPUTE(Ba, Ca, dta, ua, tb);
    LOADB(Ba, Ca, dta, ua, tA);
    COMPUTE(Bb, Cb, dtb, ub, tb + 4);
    LOADB(Bb, Cb, dtb, ub, tB);
  }
#undef LOADB
#undef COMPUTE
}

// ---------------------------------------------------------------------------
extern "C" void kernel_launch(void* const* d_in, const int* in_sizes, int n_in,
                              void* d_out, int out_size, void* d_ws, size_t ws_size,
                              hipStream_t stream) {
  const float* x         = (const float*)d_in[0];
  const float* A_log     = (const float*)d_in[1];
  const float* x_proj_w  = (const float*)d_in[2];   // (768, 256)
  const float* dt_proj_w = (const float*)d_in[3];   // (128, 768)
  const float* dt_proj_b = (const float*)d_in[4];   // (768)
  const float* conv_w    = (const float*)d_in[5];   // (768,1,4)
  const float* conv_b    = (const float*)d_in[6];   // (768)
  const float* out_w     = (const float*)d_in[7];   // (768, 768)
  float* out = (float*)d_out;
  float* ws  = (float*)d_ws;

  const int M = BSZ * SEQ;                  // 16384 rows
  // ws layout (floats)
  float* xc   = ws;                         // 12,582,912
  float* xdbl = xc + (size_t)M * DM;        //  4,194,304
  float* SL   = xdbl + (size_t)M * 256;     //  3,145,728
  float* Pd   = SL + (size_t)NC * BDN;      //  3,145,728
  float* p4   = Pd + (size_t)NC * BDN;
  unsigned short* xch = (unsigned short*)p4;                 // M*DM ushort
  unsigned short* xcl = xch + (size_t)M * DM;
  unsigned short* dth = xcl + (size_t)M * DM;                // M*128
  unsigned short* dtl = dth + (size_t)M * DTR;
  unsigned short* wTh = dtl + (size_t)M * DTR;               // 884736
  unsigned short* wTl = wTh + 884736;
  float* dtb  = out;                        // dt lives in d_out

  const size_t need_t3 = ((size_t)M * DM + (size_t)M * 256) * 4;
  const size_t need_t2 = need_t3 + 2 * (size_t)NC * BDN * 4;
  const size_t need_t1 = need_t2 + ((size_t)M * DM * 2 + (size_t)M * DTR * 2
                                    + 2 * 884736) * 2;
  const int tier = (ws_size >= need_t1) ? 1 : (ws_size >= need_t2) ? 2 : 3;

  if (tier == 1) {
    // weight split+transpose (hi/lo bf16, [N][K])
    cvt_wT<<<(768 * 256 + 255) / 256, 256, 0, stream>>>(x_proj_w, wTh, wTl, 768, 256);
    cvt_wT<<<(128 * 768 + 255) / 256, 256, 0, stream>>>(dt_proj_w, wTh + 196608, wTl + 196608, 128, 768);
    cvt_wT<<<(768 * 768 + 255) / 256, 256, 0, stream>>>(out_w, wTh + 294912, wTl + 294912, 768, 768);
    // conv + silu (+ hi/lo emit)
    int total = BSZ * SEQ * (DM / 4);
    conv_silu_kernel<<<(total + 255) / 256, 256, 0, stream>>>(x, conv_w, conv_b, xc, xch, xcl);
    // x_dbl = xc @ x_proj_w  (MFMA split)
    {
      dim3 g(M / 128, 256 / 128);
      gemm_bfs<0><<<g, 256, 0, stream>>>(xch, xcl, wTh, wTl, xdbl, DM, 256, nullptr);
    }
    // dt_raw split
    cvt_dtraw<<<(M * 32 + 255) / 256, 256, 0, stream>>>(xdbl, dth, dtl);
    // dt = softplus(dt_raw @ dt_proj_w + b)
    {
      dim3 g(M / 128, DM / 128);
      gemm_bfs<1><<<g, 256, 0, stream>>>(dth, dtl, wTh + 196608, wTl + 196608, dtb, DTR, DM, dt_proj_b);
    }
    // chunked scan; passC emits y (fp32, in-place) + y hi/lo into xch/xcl
    {
      dim3 gA(DM / 32, BSZ, NC);
      scan_passA<<<gA, 256, 0, stream>>>(xdbl, dtb, xc, A_log, SL, Pd);
      scan_combine<<<BDN / 256, 256, 0, stream>>>(SL, Pd);
      scan_passC<<<gA, 256, 0, stream>>>(xdbl, dtb, xc, A_log, SL, xch, xcl);
    }
    // out = y @ out_w
    {
      dim3 g(M / 128, DM / 128);
      gemm_bfs<0><<<g, 256, 0, stream>>>(xch, xcl, wTh + 294912, wTl + 294912, out, DM, DM, nullptr);
    }
    return;
  }

  // ---- fallback tiers: fp32 GEMMs ----
  {
    int total = BSZ * SEQ * (DM / 4);
    conv_silu_kernel<<<(total + 255) / 256, 256, 0, stream>>>(x, conv_w, conv_b, xc, nullptr, nullptr);
  }
  {
    dim3 g(M / 128, 256 / 64);
    gemm_f32<0><<<g, 256, 0, stream>>>(xc, DM, x_proj_w, 256, xdbl, 256, M, 256, DM, nullptr);
  }
  {
    dim3 g(M / 128, DM / 64);
    gemm_f32<1><<<g, 256, 0, stream>>>(xdbl, 256, dt_proj_w, DM, dtb, DM, M, DM, DTR, dt_proj_b);
  }
  if (tier == 2) {
    dim3 gA(DM / 32, BSZ, NC);
    scan_passA<<<gA, 256, 0, stream>>>(xdbl, dtb, xc, A_log, SL, Pd);
    scan_combine<<<BDN / 256, 256, 0, stream>>>(SL, Pd);
    scan_passC<<<gA, 256, 0, stream>>>(xdbl, dtb, xc, A_log, SL, nullptr, nullptr);
  } else {
    dim3 g(DM / 16, BSZ);
    scan_kernel<<<g, 256, 0, stream>>>(xdbl, dtb, xc, A_log);
  }
  {
    dim3 g(M / 128, DM / 64);
    gemm_f32<0><<<g, 256, 0, stream>>>(xc, DM, out_w, DM, out, DM, M, DM, DM, nullptr);
  }
}